// Round 16
// baseline (128.961 us; speedup 1.0000x reference)
//
#include <hip/hip_runtime.h>

// MHA fused forward: B=2,S=2048,D=1024,H=16,DK=64, causal, scores *= 8.
// Pipeline: cvt_w -> 3x proj GEMM (fp32 A fused cvt, XCD-remapped) ->
//           attn (2-way KV-SPLIT) -> merge -> out GEMM (XCD-remapped).
// R16: proj/out were latency-bound (proj 3 blocks/CU Occ26% Mfma20%; out 1/CU).
// Narrow tiles 128x128 -> 128x64: proj grid 768->1536 (6/CU), out 256->512
// (2/CU). Same K-loop structure; B-staging halves; XCD panel mapping kept.

typedef float f32x4 __attribute__((ext_vector_type(4)));
typedef float f32x16 __attribute__((ext_vector_type(16)));
typedef unsigned int u32x4 __attribute__((ext_vector_type(4)));
typedef _Float16 f16x8 __attribute__((ext_vector_type(8)));
typedef __fp16 fp16x2 __attribute__((ext_vector_type(2)));

#define DEV static __device__ __forceinline__

DEV unsigned short f2h(float x) {
  _Float16 h = (_Float16)x;
  union { _Float16 h; unsigned short u; } v; v.h = h;
  return v.u;
}

DEV unsigned pkrtz(float a, float b) {
  union { fp16x2 h; unsigned u; } v;
  v.h = __builtin_amdgcn_cvt_pkrtz(a, b);
  return v.u;
}

DEV float fexp2(float x) { return __builtin_amdgcn_exp2f(x); }  // raw v_exp_f32

DEV void pswap(unsigned& a, unsigned& b) {
  auto r = __builtin_amdgcn_permlane32_swap(a, b, false, false);
  a = r[0]; b = r[1];
}

DEV void swap_pair(float v, float& x, float& y) {
  union { float f; unsigned u; } in; in.f = v;
  auto r = __builtin_amdgcn_permlane32_swap(in.u, in.u, false, false);
  union { unsigned u; float f; } ox, oy; ox.u = r[0]; oy.u = r[1];
  x = ox.f; y = oy.f;
}

DEV f16x8 mkfrag(unsigned a, unsigned b, unsigned c, unsigned d) {
  union { unsigned u[4]; f16x8 v; } z;
  z.u[0] = a; z.u[1] = b; z.u[2] = c; z.u[3] = d;
  return z.v;
}

DEV void mfma16(f32x4& d, u32x4 a, u32x4 b) {
  asm("v_mfma_f32_16x16x32_f16 %0, %1, %2, %0" : "+v"(d) : "v"(a), "v"(b));
}

DEV void gload16(const void* g, void* l) {
  __builtin_amdgcn_global_load_lds(
      (const __attribute__((address_space(1))) unsigned int*)g,
      (__attribute__((address_space(3))) unsigned int*)l, 16, 0, 0);
}

// 8 fp32 -> 8 fp16 (RNE) packed as one 16B LDS write payload
DEV u32x4 cvt8(float4 a, float4 b) {
  union { unsigned short us[8]; u32x4 v; } z;
  z.us[0] = f2h(a.x); z.us[1] = f2h(a.y); z.us[2] = f2h(a.z); z.us[3] = f2h(a.w);
  z.us[4] = f2h(b.x); z.us[5] = f2h(b.y); z.us[6] = f2h(b.z); z.us[7] = f2h(b.w);
  return z.v;
}

#define VMCNT0() asm volatile("s_waitcnt vmcnt(0)" ::: "memory")
#define LGKMCNT0() asm volatile("s_waitcnt lgkmcnt(0)" ::: "memory")
#define NOPG(a,b,c,d)  asm volatile("s_nop 7\n\ts_nop 7" : "+v"(a), "+v"(b), "+v"(c), "+v"(d))

// ---------------- fp32 -> fp16 convert, WEIGHTS ONLY (wk,wq,wv,wo) -----------
__global__ __launch_bounds__(256) void cvt_w(
    const float* __restrict__ wk, const float* __restrict__ wq,
    const float* __restrict__ wv, const float* __restrict__ wo,
    unsigned short* __restrict__ dst) {
  const int i = (blockIdx.x * 256 + threadIdx.x) * 4;  // < 4194304
  const float* src; int off;
  if (i < 1048576)      { src = wk; off = 0; }
  else if (i < 2097152) { src = wq; off = 1048576; }
  else if (i < 3145728) { src = wv; off = 2097152; }
  else                  { src = wo; off = 3145728; }
  float4 val = *(const float4*)(src + (i - off));
  ushort4 o;
  o.x = f2h(val.x); o.y = f2h(val.y); o.z = f2h(val.z); o.w = f2h(val.w);
  *(ushort4*)(dst + i) = o;
}

// ---------------- proj GEMM: 128x64 tile, fp32 A (fused cvt), fp16 W ---------
// A tile 128xBK32 reg-staged (cvt8 -> ds_write); B tile 64xBK32 via gload_lds.
// Per wave: 64x32 output = acc[4][2].
DEV void proj_body(const float* __restrict__ A, const unsigned short* __restrict__ W,
                   const float* __restrict__ bias, void* __restrict__ out, int mode,
                   float oscale, int m0, int n0) {
  __shared__ alignas(16) char lds_a[2][8192];
  __shared__ alignas(16) char lds_b[2][4096];
  const int t = threadIdx.x;
  const int l = t & 63, g = l >> 4, c = l & 15, w = t >> 6;
  const int wr = w >> 1, wc = w & 1;

  f32x4 acc[4][2] = {};

  const int i0 = t, i1 = t + 256;
  const int ar0 = i0 >> 2, as0 = (i0 & 3) ^ (ar0 & 3);
  const int ar1 = i1 >> 2, as1 = (i1 & 3) ^ (ar1 & 3);
  const float* gaf0 = A + (long)(m0 + ar0) * 1024 + as0 * 8;
  const float* gaf1 = A + (long)(m0 + ar1) * 1024 + as1 * 8;
  const unsigned short* gb0 = W + (long)(n0 + ar0) * 1024 + as0 * 8;  // rows 0..63
  const int lo0 = i0 * 16, lo1 = i1 * 16;

  int aoff[4], boff[2];
#pragma unroll
  for (int i = 0; i < 4; i++) {
    const int ra = (wr << 6) + (i << 4) + c;
    aoff[i] = ra * 64 + ((g << 4) ^ ((ra & 3) << 4));
  }
#pragma unroll
  for (int j = 0; j < 2; j++) {
    const int rb = (wc << 5) + (j << 4) + c;
    boff[j] = rb * 64 + ((g << 4) ^ ((rb & 3) << 4));
  }

  float4 r0a = *(const float4*)(gaf0);
  float4 r0b = *(const float4*)(gaf0 + 4);
  float4 r1a = *(const float4*)(gaf1);
  float4 r1b = *(const float4*)(gaf1 + 4);
  gload16(gb0, lds_b[0] + lo0);

  for (int kt = 0; kt < 32; kt++) {
    const int cur = kt & 1;
    VMCNT0();                         // A-regs(kt) + B(kt) landed
    *(u32x4*)(lds_a[cur] + lo0) = cvt8(r0a, r0b);
    *(u32x4*)(lds_a[cur] + lo1) = cvt8(r1a, r1b);
    if (kt + 1 < 32) {
      const int o = (kt + 1) << 5;
      r0a = *(const float4*)(gaf0 + o);
      r0b = *(const float4*)(gaf0 + o + 4);
      r1a = *(const float4*)(gaf1 + o);
      r1b = *(const float4*)(gaf1 + o + 4);
    }
    LGKMCNT0();
    __builtin_amdgcn_s_barrier();
    if (kt + 1 < 32) {
      gload16(gb0 + ((kt + 1) << 5), lds_b[cur ^ 1] + lo0);
    }
    u32x4 af[4], bf[2];
#pragma unroll
    for (int i = 0; i < 4; i++) af[i] = *(const u32x4*)(lds_a[cur] + aoff[i]);
#pragma unroll
    for (int j = 0; j < 2; j++) bf[j] = *(const u32x4*)(lds_b[cur] + boff[j]);
#pragma unroll
    for (int i = 0; i < 4; i++)
#pragma unroll
      for (int j = 0; j < 2; j++)
        mfma16(acc[i][j], af[i], bf[j]);
  }

  NOPG(acc[0][0], acc[0][1], acc[1][0], acc[1][1]);
  NOPG(acc[2][0], acc[2][1], acc[3][0], acc[3][1]);

  if (mode == 1) {  // V^T layout
#pragma unroll
    for (int j = 0; j < 2; j++) {
      const int n = n0 + (wc << 5) + (j << 4) + c;
      const float bb = bias[n];
      const int h = n >> 6, d = n & 63;
#pragma unroll
      for (int i = 0; i < 4; i++) {
        const int m = m0 + (wr << 6) + (i << 4) + (g << 2);
        const int b = m >> 11, s = m & 2047;
        ushort4 o;
        o.x = f2h(acc[i][j][0] + bb);
        o.y = f2h(acc[i][j][1] + bb);
        o.z = f2h(acc[i][j][2] + bb);
        o.w = f2h(acc[i][j][3] + bb);
        *(ushort4*)&((unsigned short*)out)[((long)((b << 4) + h) * 64 + d) * 2048 + s] = o;
      }
    }
  } else {
#pragma unroll
    for (int j = 0; j < 2; j++) {
      const int n = n0 + (wc << 5) + (j << 4) + c;
      const float bb = bias[n];
#pragma unroll
      for (int i = 0; i < 4; i++) {
#pragma unroll
        for (int r = 0; r < 4; r++) {
          const int m = m0 + (wr << 6) + (i << 4) + (g << 2) + r;
          const float val = (acc[i][j][r] + bb) * oscale;
          const int b = m >> 11, s = m & 2047;
          const int h = n >> 6, d = n & 63;
          ((unsigned short*)out)[((long)((b << 4) + h) * 2048 + s) * 64 + d] = f2h(val);
        }
      }
    }
  }
}

// Grid 1536: bid = n*96 + (m*3 + z), n 0..15 (64-col tiles), m 0..31, z 0..2.
// A-panel (m,z) sharers spaced 96 (0 mod 8) -> same XCD.
__global__ __launch_bounds__(256) void gemm_proj(
    const float* kf, const float* qf, const float* vf,
    const unsigned short* wkb, const unsigned short* wqb, const unsigned short* wvb,
    const float* bk, const float* bq, const float* bvv,
    unsigned short* Kp, unsigned short* Qp, unsigned short* VpT) {
  const int bid = blockIdx.x;
  const int n = bid / 96;
  const int gg = bid % 96;
  const int m = gg / 3;
  const int z = gg % 3;
  const float* A = (z == 0) ? kf : (z == 1) ? qf : vf;
  const unsigned short* W = (z == 0) ? wkb : (z == 1) ? wqb : wvb;
  const float* bias = (z == 0) ? bk : (z == 1) ? bq : bvv;
  void* out = (z == 0) ? (void*)Kp : (z == 1) ? (void*)Qp : (void*)VpT;
  const float sc = (z == 1) ? 11.5415603271f : 1.0f;   // 8*log2(e) folded into Q
  proj_body(A, W, bias, out, (z == 2) ? 1 : 0, sc, m << 7, n << 6);
}

// ---------------- out GEMM: 128x64 tile, fp16 A x fp16 W -> fp32 -------------
// Grid 512: bid = n*32 + m (n 0..15, m 0..31); A-panel sharers same XCD.
__global__ __launch_bounds__(256) void gemm_out(
    const unsigned short* __restrict__ A, const unsigned short* __restrict__ W,
    const float* __restrict__ bias, float* __restrict__ out) {
  __shared__ alignas(16) char lds_a[2][8192];
  __shared__ alignas(16) char lds_b[2][4096];
  const int t = threadIdx.x;
  const int l = t & 63, g = l >> 4, c = l & 15, w = t >> 6;
  const int wr = w >> 1, wc = w & 1;
  const int bid = blockIdx.x;
  const int m0 = (bid & 31) << 7, n0 = (bid >> 5) << 6;

  f32x4 acc[4][2] = {};

  const int i0 = t, i1 = t + 256;
  const int ar0 = i0 >> 2, as0 = (i0 & 3) ^ (ar0 & 3);
  const int ar1 = i1 >> 2, as1 = (i1 & 3) ^ (ar1 & 3);
  const unsigned short* ga0 = A + (long)(m0 + ar0) * 1024 + as0 * 8;
  const unsigned short* ga1 = A + (long)(m0 + ar1) * 1024 + as1 * 8;
  const unsigned short* gb0 = W + (long)(n0 + ar0) * 1024 + as0 * 8;
  const int lo0 = i0 * 16, lo1 = i1 * 16;

  int aoff[4], boff[2];
#pragma unroll
  for (int i = 0; i < 4; i++) {
    const int ra = (wr << 6) + (i << 4) + c;
    aoff[i] = ra * 64 + ((g << 4) ^ ((ra & 3) << 4));
  }
#pragma unroll
  for (int j = 0; j < 2; j++) {
    const int rb = (wc << 5) + (j << 4) + c;
    boff[j] = rb * 64 + ((g << 4) ^ ((rb & 3) << 4));
  }

  gload16(ga0, lds_a[0] + lo0);
  gload16(ga1, lds_a[0] + lo1);
  gload16(gb0, lds_b[0] + lo0);

  for (int kt = 0; kt < 32; kt++) {
    const int cur = kt & 1;
    VMCNT0();
    __builtin_amdgcn_s_barrier();
    if (kt + 1 < 32) {
      gload16(ga0 + ((kt + 1) << 5), lds_a[cur ^ 1] + lo0);
      gload16(ga1 + ((kt + 1) << 5), lds_a[cur ^ 1] + lo1);
      gload16(gb0 + ((kt + 1) << 5), lds_b[cur ^ 1] + lo0);
    }
    u32x4 af[4], bf[2];
#pragma unroll
    for (int i = 0; i < 4; i++) af[i] = *(const u32x4*)(lds_a[cur] + aoff[i]);
#pragma unroll
    for (int j = 0; j < 2; j++) bf[j] = *(const u32x4*)(lds_b[cur] + boff[j]);
#pragma unroll
    for (int i = 0; i < 4; i++)
#pragma unroll
      for (int j = 0; j < 2; j++)
        mfma16(acc[i][j], af[i], bf[j]);
  }

  NOPG(acc[0][0], acc[0][1], acc[1][0], acc[1][1]);
  NOPG(acc[2][0], acc[2][1], acc[3][0], acc[3][1]);

#pragma unroll
  for (int j = 0; j < 2; j++) {
    const int n = n0 + (wc << 5) + (j << 4) + c;
    const float bb = bias[n];
#pragma unroll
    for (int i = 0; i < 4; i++) {
#pragma unroll
      for (int r = 0; r < 4; r++) {
        const int m = m0 + (wr << 6) + (i << 4) + (g << 2) + r;
        out[(long)m * 1024 + n] = acc[i][j][r] + bb;
      }
    }
  }
}

// ---------------- flash attention, 2-way KV-SPLIT (R11 loop body) ------------
__global__ __launch_bounds__(128) void attn_kernel(
    const unsigned short* __restrict__ Qp, const unsigned short* __restrict__ Kp,
    const unsigned short* __restrict__ VpT, unsigned short* __restrict__ O0,
    unsigned short* __restrict__ O1, float2* __restrict__ ml0,
    float2* __restrict__ ml1) {
  __shared__ alignas(16) char lds_k[2][8192];  // K tile [64 kv][64 d], swizzled
  __shared__ alignas(16) char lds_v[2][8192];  // V^T tile [64 d][64 kv], swizzled

  const int t = threadIdx.x;
  const int lane = t & 63, w = t >> 6;
  const int hi = lane >> 5, c32 = lane & 31;
  const int bh = blockIdx.x;
  const int qt = 31 - (int)blockIdx.y;         // longest first (LPT)
  const int sp = blockIdx.z;
  const int h0 = (qt + 2) >> 1;                // tiles in split 0
  const int tb = sp ? h0 : 0;
  const int ntiles = sp ? (qt + 1 - h0) : h0;
  const int qs = (qt << 6) + (w << 5);

  unsigned short* Op = sp ? O1 : O0;
  float2* mlp = sp ? ml1 : ml0;

  if (ntiles == 0) {                           // only split 1 at qt=0: sentinel
    if (hi == 0) mlp[bh * 2048 + qs + c32] = make_float2(-1e30f, 0.0f);
    return;
  }

  const unsigned short* gk[4]; const unsigned short* gv[4]; int lofs[4];
#pragma unroll
  for (int n = 0; n < 4; n++) {
    const int idx = t + 128 * n;
    const int row = idx >> 3, sl = (idx & 7) ^ (row & 7);
    gk[n] = Kp + ((long)bh * 2048 + row) * 64 + sl * 8;
    gv[n] = VpT + ((long)bh * 64 + row) * 2048 + sl * 8;
    lofs[n] = idx * 16;
  }

  int koff[2][4];
#pragma unroll
  for (int x = 0; x < 2; x++)
#pragma unroll
    for (int y = 0; y < 4; y++) {
      const int row = 32 * x + c32;
      koff[x][y] = row * 128 + ((((y << 1) + hi) << 4) ^ ((row & 7) << 4));
    }

  const unsigned short* qrow = Qp + ((long)bh * 2048 + qs + c32) * 64 + hi * 8;
  f16x8 qf[4];
#pragma unroll
  for (int ks = 0; ks < 4; ks++) qf[ks] = *(const f16x8*)(qrow + ks * 16);

  f32x16 oT0 = {}, oT1 = {};
  float mrun = -1e30f, lrun = 0.f;
  const int qloc = (qs & 63) + c32;

  {
    const long kb = (long)tb << 6;
#pragma unroll
    for (int n = 0; n < 4; n++) {
      gload16(gk[n] + kb * 64, lds_k[0] + lofs[n]);
      gload16(gv[n] + kb,      lds_v[0] + lofs[n]);
    }
  }

  for (int tt = 0; tt < ntiles; tt++) {
    const int cur = tt & 1;
    VMCNT0();
    __builtin_amdgcn_s_barrier();
    if (tt + 1 < ntiles) {
      const long kvn = (long)(tb + tt + 1) << 6;
#pragma unroll
      for (int n = 0; n < 4; n++) {
        gload16(gk[n] + kvn * 64, lds_k[cur ^ 1] + lofs[n]);
        gload16(gv[n] + kvn,      lds_v[cur ^ 1] + lofs[n]);
      }
    }

    f32x16 s0 = {}, s1 = {};
    __builtin_amdgcn_s_setprio(1);
#pragma unroll
    for (int ks = 0; ks < 4; ks++) {
      const f16x8 a0 = *(const f16x8*)(lds_k[cur] + koff[0][ks]);
      const f16x8 a1 = *(const f16x8*)(lds_k[cur] + koff[1][ks]);
      s0 = __builtin_amdgcn_mfma_f32_32x32x16_f16(a0, qf[ks], s0, 0, 0, 0);
      s1 = __builtin_amdgcn_mfma_f32_32x32x16_f16(a1, qf[ks], s1, 0, 0, 0);
    }
    __builtin_amdgcn_s_setprio(0);

    if (tb + tt == qt) {
#pragma unroll
      for (int r = 0; r < 16; r++) {
        const int kvc = (r & 3) + 8 * (r >> 2) + 4 * hi;
        if (kvc > qloc)      s0[r] = -1e30f;
        if (kvc + 32 > qloc) s1[r] = -1e30f;
      }
    }

    float tm[16];
#pragma unroll
    for (int r = 0; r < 16; r++) tm[r] = fmaxf(s0[r], s1[r]);
#pragma unroll
    for (int d = 8; d >= 1; d >>= 1)
#pragma unroll
      for (int r = 0; r < 8; r++)
        if (r < d) tm[r] = fmaxf(tm[r], tm[r + d]);
    float x, y;
    swap_pair(tm[0], x, y);
    const float pmax = fmaxf(x, y);

    if (!__all(pmax - mrun <= 8.0f)) {
      const float mnew = fmaxf(mrun, pmax);
      const float corr = fexp2(mrun - mnew);
      mrun = mnew;
      lrun *= corr;
      oT0 *= corr;
      oT1 *= corr;
    }

#pragma unroll
    for (int r = 0; r < 16; r++) {
      s0[r] = fexp2(s0[r] - mrun);
      s1[r] = fexp2(s1[r] - mrun);
    }
    float ts[16];
#pragma unroll
    for (int r = 0; r < 16; r++) ts[r] = s0[r] + s1[r];
#pragma unroll
    for (int d = 8; d >= 1; d >>= 1)
#pragma unroll
      for (int r = 0; r < 8; r++)
        if (r < d) ts[r] = ts[r] + ts[r + d];
    lrun += ts[0];

    unsigned pk[8];
#pragma unroll
    for (int m = 0; m < 8; m++) pk[m] = pkrtz(s0[2 * m], s0[2 * m + 1]);
    pswap(pk[0], pk[2]); pswap(pk[1], pk[3]);
    pswap(pk[4], pk[6]); pswap(pk[5], pk[7]);
    const f16x8 pf0 = mkfrag(pk[0], pk[1], pk[2], pk[3]);
    const f16x8 pf1 = mkfrag(pk[4], pk[5], pk[6], pk[7]);
#pragma unroll
    for (int m = 0; m < 8; m++) pk[m] = pkrtz(s1[2 * m], s1[2 * m + 1]);
    pswap(pk[0], pk[2]); pswap(pk[1], pk[3]);
    pswap(pk[4], pk[6]); pswap(pk[5], pk[7]);
    const f16x8 pf2 = mkfrag(pk[0], pk[1], pk[2], pk[3]);
    const f16x8 pf3 = mkfrag(pk[4], pk[5], pk[6], pk[7]);

    __builtin_amdgcn_s_setprio(1);
    {
      const f16x8 v00 = *(const f16x8*)(lds_v[cur] + koff[0][0]);
      const f16x8 v01 = *(const f16x8*)(lds_v[cur] + koff[0][1]);
      const f16x8 v02 = *(const f16x8*)(lds_v[cur] + koff[0][2]);
      const f16x8 v03 = *(const f16x8*)(lds_v[cur] + koff[0][3]);
      oT0 = __builtin_amdgcn_mfma_f32_32x32x16_f16(v00, pf0, oT0, 0, 0, 0);
      oT0 = __builtin_amdgcn_mfma_f32_32x32x16_f16(v01, pf1, oT0, 0, 0, 0);
      oT0 = __builtin_amdgcn_mfma_f32_32x32x16_f16(v02, pf2, oT0, 0, 0, 0);
      oT0 = __builtin_amdgcn_mfma_f32_32x32x16_f16(v03, pf3, oT0, 0, 0, 0);
      const f16x8 v10 = *(const f16x8*)(lds_v[cur] + koff[1][0]);
      const f16x8 v11 = *(const f16x8*)(lds_v[cur] + koff[1][1]);
      const f16x8 v12 = *(const f16x8*)(lds_v[cur] + koff[1][2]);
      const f16x8 v13 = *(const f16x8*)(lds_v[cur] + koff[1][3]);
      oT1 = __builtin_amdgcn_mfma_f32_32x32x16_f16(v10, pf0, oT1, 0, 0, 0);
      oT1 = __builtin_amdgcn_mfma_f32_32x32x16_f16(v11, pf1, oT1, 0, 0, 0);
      oT1 = __builtin_amdgcn_mfma_f32_32x32x16_f16(v12, pf2, oT1, 0, 0, 0);
      oT1 = __builtin_amdgcn_mfma_f32_32x32x16_f16(v13, pf3, oT1, 0, 0, 0);
    }
    __builtin_amdgcn_s_setprio(0);
  }

  float sx, sy;
  swap_pair(lrun, sx, sy);
  const float lsum = sx + sy;
  const float inv = 1.0f / lsum;
  const int b = bh >> 4, h = bh & 15;
  const long rowbase = ((long)b * 2048 + qs + c32) * 1024 + (h << 6);
#pragma unroll
  for (int dt = 0; dt < 2; dt++) {
#pragma unroll
    for (int g4 = 0; g4 < 4; g4++) {
      const f32x16& o = dt ? oT1 : oT0;
      uint2 pkd;
      pkd.x = pkrtz(o[4 * g4 + 0] * inv, o[4 * g4 + 1] * inv);
      pkd.y = pkrtz(o[4 * g4 + 2] * inv, o[4 * g4 + 3] * inv);
      *(uint2*)&Op[rowbase + 32 * dt + 8 * g4 + 4 * hi] = pkd;
    }
  }
  if (hi == 0) mlp[bh * 2048 + qs + c32] = make_float2(mrun, lsum);
}

// ---------------- merge: O0 = a0*O0 + a1*O1 (in place) -----------------------
__global__ __launch_bounds__(256) void merge_o(
    unsigned short* __restrict__ O0, const unsigned short* __restrict__ O1,
    const float2* __restrict__ ml0, const float2* __restrict__ ml1) {
  const int idx = (blockIdx.x * 256 + threadIdx.x) * 8;   // < 4194304
  const int d = idx & 1023;
  const int s = (idx >> 10) & 2047;
  const int b = idx >> 21;
  const int bh = (b << 4) + (d >> 6);
  const float2 a = ml0[bh * 2048 + s];
  const float2 c = ml1[bh * 2048 + s];
  if (c.y == 0.0f) return;               // split-1 empty: O0 already final
  const float M = fmaxf(a.x, c.x);
  float w0 = a.y * fexp2(a.x - M);
  float w1 = c.y * fexp2(c.x - M);
  const float inv = 1.0f / (w0 + w1);
  w0 *= inv; w1 *= inv;
  const f16x8 o0 = *(const f16x8*)&O0[idx];
  const f16x8 o1 = *(const f16x8*)&O1[idx];
  uint4 r;
  r.x = pkrtz(w0 * (float)o0[0] + w1 * (float)o1[0],
              w0 * (float)o0[1] + w1 * (float)o1[1]);
  r.y = pkrtz(w0 * (float)o0[2] + w1 * (float)o1[2],
              w0 * (float)o0[3] + w1 * (float)o1[3]);
  r.z = pkrtz(w0 * (float)o0[4] + w1 * (float)o1[4],
              w0 * (float)o0[5] + w1 * (float)o1[5]);
  r.w = pkrtz(w0 * (float)o0[6] + w1 * (float)o1[6],
              w0 * (float)o0[7] + w1 * (float)o1[7]);
  *(uint4*)&O0[idx] = r;
}

// ---------------- launch ------------------------------------------------------
extern "C" void kernel_launch(void* const* d_in, const int* in_sizes, int n_in,
                              void* d_out, int out_size, void* d_ws, size_t ws_size,
                              hipStream_t stream) {
  (void)in_sizes; (void)n_in; (void)out_size; (void)ws_size;
  const float* kin = (const float*)d_in[0];
  const float* qin = (const float*)d_in[1];
  const float* vin = (const float*)d_in[2];
  const float* wk  = (const float*)d_in[4];
  const float* bk  = (const float*)d_in[5];
  const float* wq  = (const float*)d_in[6];
  const float* bq  = (const float*)d_in[7];
  const float* wv  = (const float*)d_in[8];
  const float* bv  = (const float*)d_in[9];
  const float* wo  = (const float*)d_in[10];
  const float* bo  = (const float*)d_in[11];

  unsigned short* ws  = (unsigned short*)d_ws;
  unsigned short* O1  = ws;                        // [B,S,D] fp16 partial (split 1)
  float2* ml0 = (float2*)(ws + 4194304);           // 65536 x float2
  float2* ml1 = (float2*)(ws + 4456448);
  unsigned short* wkb = ws + 12582912;             // fp16 weights
  unsigned short* wqb = ws + 13631488;
  unsigned short* wvb = ws + 14680064;
  unsigned short* wob = ws + 15728640;
  unsigned short* Kp  = ws + 16777216;             // [B,H,S,64]
  unsigned short* Qp  = ws + 20971520;             // [B,H,S,64], pre-scaled 8*log2e
  unsigned short* VpT = ws + 25165824;             // [B,H,64,S]
  unsigned short* Oo  = ws + 29360128;             // [B,S,D] fp16 (split-0 / final)

  cvt_w<<<4096, 256, 0, stream>>>(wk, wq, wv, wo, wkb);
  gemm_proj<<<1536, 256, 0, stream>>>(kin, qin, vin, wkb, wqb, wvb,
                                      bk, bq, bv, Kp, Qp, VpT);
  attn_kernel<<<dim3(32, 32, 2), 128, 0, stream>>>(Qp, Kp, VpT, Oo, O1, ml0, ml1);
  merge_o<<<2048, 256, 0, stream>>>(Oo, O1, ml0, ml1);
  gemm_out<<<512, 256, 0, stream>>>(Oo, wob, bo, (float*)d_out);
}

// Round 18
// 114.915 us; speedup vs baseline: 1.1222x; 1.1222x over previous
//
#include <hip/hip_runtime.h>

// MHA fused forward: B=2,S=2048,D=1024,H=16,DK=64, causal, scores *= 8.
// Pipeline: cvt_w -> 3x proj GEMM (fp32 A fused cvt, XCD-remapped) ->
//           attn (2-way KV-SPLIT, R11 loop) -> merge -> out GEMM (XCD-remapped).
// R18: true revert to R15 (115.2us). R17's crash was a grid mismatch: 128x128
// gemm_out body (expects 256 blocks) launched with 512 -> OOB. Fixed to 256.

typedef float f32x4 __attribute__((ext_vector_type(4)));
typedef float f32x16 __attribute__((ext_vector_type(16)));
typedef unsigned int u32x4 __attribute__((ext_vector_type(4)));
typedef _Float16 f16x8 __attribute__((ext_vector_type(8)));
typedef __fp16 fp16x2 __attribute__((ext_vector_type(2)));

#define DEV static __device__ __forceinline__

DEV unsigned short f2h(float x) {
  _Float16 h = (_Float16)x;
  union { _Float16 h; unsigned short u; } v; v.h = h;
  return v.u;
}

DEV unsigned pkrtz(float a, float b) {
  union { fp16x2 h; unsigned u; } v;
  v.h = __builtin_amdgcn_cvt_pkrtz(a, b);
  return v.u;
}

DEV float fexp2(float x) { return __builtin_amdgcn_exp2f(x); }  // raw v_exp_f32

DEV void pswap(unsigned& a, unsigned& b) {
  auto r = __builtin_amdgcn_permlane32_swap(a, b, false, false);
  a = r[0]; b = r[1];
}

DEV void swap_pair(float v, float& x, float& y) {
  union { float f; unsigned u; } in; in.f = v;
  auto r = __builtin_amdgcn_permlane32_swap(in.u, in.u, false, false);
  union { unsigned u; float f; } ox, oy; ox.u = r[0]; oy.u = r[1];
  x = ox.f; y = oy.f;
}

DEV f16x8 mkfrag(unsigned a, unsigned b, unsigned c, unsigned d) {
  union { unsigned u[4]; f16x8 v; } z;
  z.u[0] = a; z.u[1] = b; z.u[2] = c; z.u[3] = d;
  return z.v;
}

DEV void mfma16(f32x4& d, u32x4 a, u32x4 b) {
  asm("v_mfma_f32_16x16x32_f16 %0, %1, %2, %0" : "+v"(d) : "v"(a), "v"(b));
}

DEV void gload16(const void* g, void* l) {
  __builtin_amdgcn_global_load_lds(
      (const __attribute__((address_space(1))) unsigned int*)g,
      (__attribute__((address_space(3))) unsigned int*)l, 16, 0, 0);
}

// 8 fp32 -> 8 fp16 (RNE) packed as one 16B LDS write payload
DEV u32x4 cvt8(float4 a, float4 b) {
  union { unsigned short us[8]; u32x4 v; } z;
  z.us[0] = f2h(a.x); z.us[1] = f2h(a.y); z.us[2] = f2h(a.z); z.us[3] = f2h(a.w);
  z.us[4] = f2h(b.x); z.us[5] = f2h(b.y); z.us[6] = f2h(b.z); z.us[7] = f2h(b.w);
  return z.v;
}

#define VMCNT0() asm volatile("s_waitcnt vmcnt(0)" ::: "memory")
#define LGKMCNT0() asm volatile("s_waitcnt lgkmcnt(0)" ::: "memory")
#define NOPG(a,b,c,d)  asm volatile("s_nop 7\n\ts_nop 7" : "+v"(a), "+v"(b), "+v"(c), "+v"(d))

// ---------------- fp32 -> fp16 convert, WEIGHTS ONLY (wk,wq,wv,wo) -----------
__global__ __launch_bounds__(256) void cvt_w(
    const float* __restrict__ wk, const float* __restrict__ wq,
    const float* __restrict__ wv, const float* __restrict__ wo,
    unsigned short* __restrict__ dst) {
  const int i = (blockIdx.x * 256 + threadIdx.x) * 4;  // < 4194304
  const float* src; int off;
  if (i < 1048576)      { src = wk; off = 0; }
  else if (i < 2097152) { src = wq; off = 1048576; }
  else if (i < 3145728) { src = wv; off = 2097152; }
  else                  { src = wo; off = 3145728; }
  float4 val = *(const float4*)(src + (i - off));
  ushort4 o;
  o.x = f2h(val.x); o.y = f2h(val.y); o.z = f2h(val.z); o.w = f2h(val.w);
  *(ushort4*)(dst + i) = o;
}

// ---------------- proj GEMM: fp32 A (fused cvt), fp16 W --------------------
DEV void proj_body(const float* __restrict__ A, const unsigned short* __restrict__ W,
                   const float* __restrict__ bias, void* __restrict__ out, int mode,
                   float oscale, int m0, int n0) {
  __shared__ alignas(16) char lds_a[2][8192];
  __shared__ alignas(16) char lds_b[2][8192];
  const int t = threadIdx.x;
  const int l = t & 63, g = l >> 4, c = l & 15, w = t >> 6;
  const int wr = w >> 1, wc = w & 1;

  f32x4 acc[4][4] = {};

  const int i0 = t, i1 = t + 256;
  const int ar0 = i0 >> 2, as0 = (i0 & 3) ^ (ar0 & 3);
  const int ar1 = i1 >> 2, as1 = (i1 & 3) ^ (ar1 & 3);
  const float* gaf0 = A + (long)(m0 + ar0) * 1024 + as0 * 8;
  const float* gaf1 = A + (long)(m0 + ar1) * 1024 + as1 * 8;
  const unsigned short* gb0 = W + (long)(n0 + ar0) * 1024 + as0 * 8;
  const unsigned short* gb1 = W + (long)(n0 + ar1) * 1024 + as1 * 8;
  const int lo0 = i0 * 16, lo1 = i1 * 16;

  int aoff[4], boff[4];
#pragma unroll
  for (int i = 0; i < 4; i++) {
    const int ra = (wr << 6) + (i << 4) + c;
    aoff[i] = ra * 64 + ((g << 4) ^ ((ra & 3) << 4));
    const int rb = (wc << 6) + (i << 4) + c;
    boff[i] = rb * 64 + ((g << 4) ^ ((rb & 3) << 4));
  }

  float4 r0a = *(const float4*)(gaf0);
  float4 r0b = *(const float4*)(gaf0 + 4);
  float4 r1a = *(const float4*)(gaf1);
  float4 r1b = *(const float4*)(gaf1 + 4);
  gload16(gb0, lds_b[0] + lo0);
  gload16(gb1, lds_b[0] + lo1);

  for (int kt = 0; kt < 32; kt++) {
    const int cur = kt & 1;
    VMCNT0();
    *(u32x4*)(lds_a[cur] + lo0) = cvt8(r0a, r0b);
    *(u32x4*)(lds_a[cur] + lo1) = cvt8(r1a, r1b);
    if (kt + 1 < 32) {
      const int o = (kt + 1) << 5;
      r0a = *(const float4*)(gaf0 + o);
      r0b = *(const float4*)(gaf0 + o + 4);
      r1a = *(const float4*)(gaf1 + o);
      r1b = *(const float4*)(gaf1 + o + 4);
    }
    LGKMCNT0();
    __builtin_amdgcn_s_barrier();
    if (kt + 1 < 32) {
      gload16(gb0 + ((kt + 1) << 5), lds_b[cur ^ 1] + lo0);
      gload16(gb1 + ((kt + 1) << 5), lds_b[cur ^ 1] + lo1);
    }
    u32x4 af[4], bf[4];
#pragma unroll
    for (int i = 0; i < 4; i++) af[i] = *(const u32x4*)(lds_a[cur] + aoff[i]);
#pragma unroll
    for (int j = 0; j < 4; j++) bf[j] = *(const u32x4*)(lds_b[cur] + boff[j]);
#pragma unroll
    for (int i = 0; i < 4; i++)
#pragma unroll
      for (int j = 0; j < 4; j++)
        mfma16(acc[i][j], af[i], bf[j]);
  }

  NOPG(acc[0][0], acc[0][1], acc[0][2], acc[0][3]);
  NOPG(acc[1][0], acc[1][1], acc[1][2], acc[1][3]);
  NOPG(acc[2][0], acc[2][1], acc[2][2], acc[2][3]);
  NOPG(acc[3][0], acc[3][1], acc[3][2], acc[3][3]);

  if (mode == 1) {  // V^T layout
#pragma unroll
    for (int j = 0; j < 4; j++) {
      const int n = n0 + (wc << 6) + (j << 4) + c;
      const float bb = bias[n];
      const int h = n >> 6, d = n & 63;
#pragma unroll
      for (int i = 0; i < 4; i++) {
        const int m = m0 + (wr << 6) + (i << 4) + (g << 2);
        const int b = m >> 11, s = m & 2047;
        ushort4 o;
        o.x = f2h(acc[i][j][0] + bb);
        o.y = f2h(acc[i][j][1] + bb);
        o.z = f2h(acc[i][j][2] + bb);
        o.w = f2h(acc[i][j][3] + bb);
        *(ushort4*)&((unsigned short*)out)[((long)((b << 4) + h) * 64 + d) * 2048 + s] = o;
      }
    }
  } else {
#pragma unroll
    for (int j = 0; j < 4; j++) {
      const int n = n0 + (wc << 6) + (j << 4) + c;
      const float bb = bias[n];
#pragma unroll
      for (int i = 0; i < 4; i++) {
#pragma unroll
        for (int r = 0; r < 4; r++) {
          const int m = m0 + (wr << 6) + (i << 4) + (g << 2) + r;
          const float val = (acc[i][j][r] + bb) * oscale;
          const int b = m >> 11, s = m & 2047;
          const int h = n >> 6, d = n & 63;
          ((unsigned short*)out)[((long)((b << 4) + h) * 2048 + s) * 64 + d] = f2h(val);
        }
      }
    }
  }
}

// bid = n*96 + (m*3 + z): A-panel sharers spaced by 96 (0 mod 8) -> same XCD.
__global__ __launch_bounds__(256) void gemm_proj(
    const float* kf, const float* qf, const float* vf,
    const unsigned short* wkb, const unsigned short* wqb, const unsigned short* wvb,
    const float* bk, const float* bq, const float* bvv,
    unsigned short* Kp, unsigned short* Qp, unsigned short* VpT) {
  const int bid = blockIdx.x;
  const int n = bid / 96;
  const int gg = bid % 96;
  const int m = gg / 3;
  const int z = gg % 3;
  const float* A = (z == 0) ? kf : (z == 1) ? qf : vf;
  const unsigned short* W = (z == 0) ? wkb : (z == 1) ? wqb : wvb;
  const float* bias = (z == 0) ? bk : (z == 1) ? bq : bvv;
  void* out = (z == 0) ? (void*)Kp : (z == 1) ? (void*)Qp : (void*)VpT;
  const float sc = (z == 1) ? 11.5415603271f : 1.0f;   // 8*log2(e) folded into Q
  proj_body(A, W, bias, out, (z == 2) ? 1 : 0, sc, m << 7, n << 7);
}

// ---------------- out GEMM: fp16 A (Oo) x fp16 W -> fp32 out ----------------
// Grid 256: bid = n*32 + m (128x128 tiles); A-panel sharers same XCD.
__global__ __launch_bounds__(256) void gemm_out(
    const unsigned short* __restrict__ A, const unsigned short* __restrict__ W,
    const float* __restrict__ bias, float* __restrict__ out) {
  __shared__ alignas(16) char lds_a[2][8192];
  __shared__ alignas(16) char lds_b[2][8192];
  const int t = threadIdx.x;
  const int l = t & 63, g = l >> 4, c = l & 15, w = t >> 6;
  const int wr = w >> 1, wc = w & 1;
  const int bid = blockIdx.x;
  const int m0 = (bid & 31) << 7, n0 = (bid >> 5) << 7;

  f32x4 acc[4][4] = {};

  const int i0 = t, i1 = t + 256;
  const int ar0 = i0 >> 2, as0 = (i0 & 3) ^ (ar0 & 3);
  const int ar1 = i1 >> 2, as1 = (i1 & 3) ^ (ar1 & 3);
  const unsigned short* ga0 = A + (long)(m0 + ar0) * 1024 + as0 * 8;
  const unsigned short* ga1 = A + (long)(m0 + ar1) * 1024 + as1 * 8;
  const unsigned short* gb0 = W + (long)(n0 + ar0) * 1024 + as0 * 8;
  const unsigned short* gb1 = W + (long)(n0 + ar1) * 1024 + as1 * 8;
  const int lo0 = i0 * 16, lo1 = i1 * 16;

  int aoff[4], boff[4];
#pragma unroll
  for (int i = 0; i < 4; i++) {
    const int ra = (wr << 6) + (i << 4) + c;
    aoff[i] = ra * 64 + ((g << 4) ^ ((ra & 3) << 4));
    const int rb = (wc << 6) + (i << 4) + c;
    boff[i] = rb * 64 + ((g << 4) ^ ((rb & 3) << 4));
  }

  gload16(ga0, lds_a[0] + lo0);
  gload16(ga1, lds_a[0] + lo1);
  gload16(gb0, lds_b[0] + lo0);
  gload16(gb1, lds_b[0] + lo1);

  for (int kt = 0; kt < 32; kt++) {
    const int cur = kt & 1;
    VMCNT0();
    __builtin_amdgcn_s_barrier();
    if (kt + 1 < 32) {
      gload16(ga0 + ((kt + 1) << 5), lds_a[cur ^ 1] + lo0);
      gload16(ga1 + ((kt + 1) << 5), lds_a[cur ^ 1] + lo1);
      gload16(gb0 + ((kt + 1) << 5), lds_b[cur ^ 1] + lo0);
      gload16(gb1 + ((kt + 1) << 5), lds_b[cur ^ 1] + lo1);
    }
    u32x4 af[4], bf[4];
#pragma unroll
    for (int i = 0; i < 4; i++) af[i] = *(const u32x4*)(lds_a[cur] + aoff[i]);
#pragma unroll
    for (int j = 0; j < 4; j++) bf[j] = *(const u32x4*)(lds_b[cur] + boff[j]);
#pragma unroll
    for (int i = 0; i < 4; i++)
#pragma unroll
      for (int j = 0; j < 4; j++)
        mfma16(acc[i][j], af[i], bf[j]);
  }

  NOPG(acc[0][0], acc[0][1], acc[0][2], acc[0][3]);
  NOPG(acc[1][0], acc[1][1], acc[1][2], acc[1][3]);
  NOPG(acc[2][0], acc[2][1], acc[2][2], acc[2][3]);
  NOPG(acc[3][0], acc[3][1], acc[3][2], acc[3][3]);

#pragma unroll
  for (int j = 0; j < 4; j++) {
    const int n = n0 + (wc << 6) + (j << 4) + c;
    const float bb = bias[n];
#pragma unroll
    for (int i = 0; i < 4; i++) {
#pragma unroll
      for (int r = 0; r < 4; r++) {
        const int m = m0 + (wr << 6) + (i << 4) + (g << 2) + r;
        out[(long)m * 1024 + n] = acc[i][j][r] + bb;
      }
    }
  }
}

// ---------------- flash attention, 2-way KV-SPLIT (R11 loop body) ------------
__global__ __launch_bounds__(128) void attn_kernel(
    const unsigned short* __restrict__ Qp, const unsigned short* __restrict__ Kp,
    const unsigned short* __restrict__ VpT, unsigned short* __restrict__ O0,
    unsigned short* __restrict__ O1, float2* __restrict__ ml0,
    float2* __restrict__ ml1) {
  __shared__ alignas(16) char lds_k[2][8192];  // K tile [64 kv][64 d], swizzled
  __shared__ alignas(16) char lds_v[2][8192];  // V^T tile [64 d][64 kv], swizzled

  const int t = threadIdx.x;
  const int lane = t & 63, w = t >> 6;
  const int hi = lane >> 5, c32 = lane & 31;
  const int bh = blockIdx.x;
  const int qt = 31 - (int)blockIdx.y;         // longest first (LPT)
  const int sp = blockIdx.z;
  const int h0 = (qt + 2) >> 1;                // tiles in split 0
  const int tb = sp ? h0 : 0;
  const int ntiles = sp ? (qt + 1 - h0) : h0;
  const int qs = (qt << 6) + (w << 5);

  unsigned short* Op = sp ? O1 : O0;
  float2* mlp = sp ? ml1 : ml0;

  if (ntiles == 0) {                           // only split 1 at qt=0: sentinel
    if (hi == 0) mlp[bh * 2048 + qs + c32] = make_float2(-1e30f, 0.0f);
    return;
  }

  const unsigned short* gk[4]; const unsigned short* gv[4]; int lofs[4];
#pragma unroll
  for (int n = 0; n < 4; n++) {
    const int idx = t + 128 * n;
    const int row = idx >> 3, sl = (idx & 7) ^ (row & 7);
    gk[n] = Kp + ((long)bh * 2048 + row) * 64 + sl * 8;
    gv[n] = VpT + ((long)bh * 64 + row) * 2048 + sl * 8;
    lofs[n] = idx * 16;
  }

  int koff[2][4];
#pragma unroll
  for (int x = 0; x < 2; x++)
#pragma unroll
    for (int y = 0; y < 4; y++) {
      const int row = 32 * x + c32;
      koff[x][y] = row * 128 + ((((y << 1) + hi) << 4) ^ ((row & 7) << 4));
    }

  const unsigned short* qrow = Qp + ((long)bh * 2048 + qs + c32) * 64 + hi * 8;
  f16x8 qf[4];
#pragma unroll
  for (int ks = 0; ks < 4; ks++) qf[ks] = *(const f16x8*)(qrow + ks * 16);

  f32x16 oT0 = {}, oT1 = {};
  float mrun = -1e30f, lrun = 0.f;
  const int qloc = (qs & 63) + c32;

  {
    const long kb = (long)tb << 6;
#pragma unroll
    for (int n = 0; n < 4; n++) {
      gload16(gk[n] + kb * 64, lds_k[0] + lofs[n]);
      gload16(gv[n] + kb,      lds_v[0] + lofs[n]);
    }
  }

  for (int tt = 0; tt < ntiles; tt++) {
    const int cur = tt & 1;
    VMCNT0();
    __builtin_amdgcn_s_barrier();
    if (tt + 1 < ntiles) {
      const long kvn = (long)(tb + tt + 1) << 6;
#pragma unroll
      for (int n = 0; n < 4; n++) {
        gload16(gk[n] + kvn * 64, lds_k[cur ^ 1] + lofs[n]);
        gload16(gv[n] + kvn,      lds_v[cur ^ 1] + lofs[n]);
      }
    }

    f32x16 s0 = {}, s1 = {};
    __builtin_amdgcn_s_setprio(1);
#pragma unroll
    for (int ks = 0; ks < 4; ks++) {
      const f16x8 a0 = *(const f16x8*)(lds_k[cur] + koff[0][ks]);
      const f16x8 a1 = *(const f16x8*)(lds_k[cur] + koff[1][ks]);
      s0 = __builtin_amdgcn_mfma_f32_32x32x16_f16(a0, qf[ks], s0, 0, 0, 0);
      s1 = __builtin_amdgcn_mfma_f32_32x32x16_f16(a1, qf[ks], s1, 0, 0, 0);
    }
    __builtin_amdgcn_s_setprio(0);

    if (tb + tt == qt) {
#pragma unroll
      for (int r = 0; r < 16; r++) {
        const int kvc = (r & 3) + 8 * (r >> 2) + 4 * hi;
        if (kvc > qloc)      s0[r] = -1e30f;
        if (kvc + 32 > qloc) s1[r] = -1e30f;
      }
    }

    float tm[16];
#pragma unroll
    for (int r = 0; r < 16; r++) tm[r] = fmaxf(s0[r], s1[r]);
#pragma unroll
    for (int d = 8; d >= 1; d >>= 1)
#pragma unroll
      for (int r = 0; r < 8; r++)
        if (r < d) tm[r] = fmaxf(tm[r], tm[r + d]);
    float x, y;
    swap_pair(tm[0], x, y);
    const float pmax = fmaxf(x, y);

    if (!__all(pmax - mrun <= 8.0f)) {
      const float mnew = fmaxf(mrun, pmax);
      const float corr = fexp2(mrun - mnew);
      mrun = mnew;
      lrun *= corr;
      oT0 *= corr;
      oT1 *= corr;
    }

#pragma unroll
    for (int r = 0; r < 16; r++) {
      s0[r] = fexp2(s0[r] - mrun);
      s1[r] = fexp2(s1[r] - mrun);
    }
    float ts[16];
#pragma unroll
    for (int r = 0; r < 16; r++) ts[r] = s0[r] + s1[r];
#pragma unroll
    for (int d = 8; d >= 1; d >>= 1)
#pragma unroll
      for (int r = 0; r < 8; r++)
        if (r < d) ts[r] = ts[r] + ts[r + d];
    lrun += ts[0];

    unsigned pk[8];
#pragma unroll
    for (int m = 0; m < 8; m++) pk[m] = pkrtz(s0[2 * m], s0[2 * m + 1]);
    pswap(pk[0], pk[2]); pswap(pk[1], pk[3]);
    pswap(pk[4], pk[6]); pswap(pk[5], pk[7]);
    const f16x8 pf0 = mkfrag(pk[0], pk[1], pk[2], pk[3]);
    const f16x8 pf1 = mkfrag(pk[4], pk[5], pk[6], pk[7]);
#pragma unroll
    for (int m = 0; m < 8; m++) pk[m] = pkrtz(s1[2 * m], s1[2 * m + 1]);
    pswap(pk[0], pk[2]); pswap(pk[1], pk[3]);
    pswap(pk[4], pk[6]); pswap(pk[5], pk[7]);
    const f16x8 pf2 = mkfrag(pk[0], pk[1], pk[2], pk[3]);
    const f16x8 pf3 = mkfrag(pk[4], pk[5], pk[6], pk[7]);

    __builtin_amdgcn_s_setprio(1);
    {
      const f16x8 v00 = *(const f16x8*)(lds_v[cur] + koff[0][0]);
      const f16x8 v01 = *(const f16x8*)(lds_v[cur] + koff[0][1]);
      const f16x8 v02 = *(const f16x8*)(lds_v[cur] + koff[0][2]);
      const f16x8 v03 = *(const f16x8*)(lds_v[cur] + koff[0][3]);
      oT0 = __builtin_amdgcn_mfma_f32_32x32x16_f16(v00, pf0, oT0, 0, 0, 0);
      oT0 = __builtin_amdgcn_mfma_f32_32x32x16_f16(v01, pf1, oT0, 0, 0, 0);
      oT0 = __builtin_amdgcn_mfma_f32_32x32x16_f16(v02, pf2, oT0, 0, 0, 0);
      oT0 = __builtin_amdgcn_mfma_f32_32x32x16_f16(v03, pf3, oT0, 0, 0, 0);
      const f16x8 v10 = *(const f16x8*)(lds_v[cur] + koff[1][0]);
      const f16x8 v11 = *(const f16x8*)(lds_v[cur] + koff[1][1]);
      const f16x8 v12 = *(const f16x8*)(lds_v[cur] + koff[1][2]);
      const f16x8 v13 = *(const f16x8*)(lds_v[cur] + koff[1][3]);
      oT1 = __builtin_amdgcn_mfma_f32_32x32x16_f16(v10, pf0, oT1, 0, 0, 0);
      oT1 = __builtin_amdgcn_mfma_f32_32x32x16_f16(v11, pf1, oT1, 0, 0, 0);
      oT1 = __builtin_amdgcn_mfma_f32_32x32x16_f16(v12, pf2, oT1, 0, 0, 0);
      oT1 = __builtin_amdgcn_mfma_f32_32x32x16_f16(v13, pf3, oT1, 0, 0, 0);
    }
    __builtin_amdgcn_s_setprio(0);
  }

  float sx, sy;
  swap_pair(lrun, sx, sy);
  const float lsum = sx + sy;
  const float inv = 1.0f / lsum;
  const int b = bh >> 4, h = bh & 15;
  const long rowbase = ((long)b * 2048 + qs + c32) * 1024 + (h << 6);
#pragma unroll
  for (int dt = 0; dt < 2; dt++) {
#pragma unroll
    for (int g4 = 0; g4 < 4; g4++) {
      const f32x16& o = dt ? oT1 : oT0;
      uint2 pkd;
      pkd.x = pkrtz(o[4 * g4 + 0] * inv, o[4 * g4 + 1] * inv);
      pkd.y = pkrtz(o[4 * g4 + 2] * inv, o[4 * g4 + 3] * inv);
      *(uint2*)&Op[rowbase + 32 * dt + 8 * g4 + 4 * hi] = pkd;
    }
  }
  if (hi == 0) mlp[bh * 2048 + qs + c32] = make_float2(mrun, lsum);
}

// ---------------- merge: O0 = a0*O0 + a1*O1 (in place) -----------------------
__global__ __launch_bounds__(256) void merge_o(
    unsigned short* __restrict__ O0, const unsigned short* __restrict__ O1,
    const float2* __restrict__ ml0, const float2* __restrict__ ml1) {
  const int idx = (blockIdx.x * 256 + threadIdx.x) * 8;   // < 4194304
  const int d = idx & 1023;
  const int s = (idx >> 10) & 2047;
  const int b = idx >> 21;
  const int bh = (b << 4) + (d >> 6);
  const float2 a = ml0[bh * 2048 + s];
  const float2 c = ml1[bh * 2048 + s];
  if (c.y == 0.0f) return;               // split-1 empty: O0 already final
  const float M = fmaxf(a.x, c.x);
  float w0 = a.y * fexp2(a.x - M);
  float w1 = c.y * fexp2(c.x - M);
  const float inv = 1.0f / (w0 + w1);
  w0 *= inv; w1 *= inv;
  const f16x8 o0 = *(const f16x8*)&O0[idx];
  const f16x8 o1 = *(const f16x8*)&O1[idx];
  uint4 r;
  r.x = pkrtz(w0 * (float)o0[0] + w1 * (float)o1[0],
              w0 * (float)o0[1] + w1 * (float)o1[1]);
  r.y = pkrtz(w0 * (float)o0[2] + w1 * (float)o1[2],
              w0 * (float)o0[3] + w1 * (float)o1[3]);
  r.z = pkrtz(w0 * (float)o0[4] + w1 * (float)o1[4],
              w0 * (float)o0[5] + w1 * (float)o1[5]);
  r.w = pkrtz(w0 * (float)o0[6] + w1 * (float)o1[6],
              w0 * (float)o0[7] + w1 * (float)o1[7]);
  *(uint4*)&O0[idx] = r;
}

// ---------------- launch ------------------------------------------------------
extern "C" void kernel_launch(void* const* d_in, const int* in_sizes, int n_in,
                              void* d_out, int out_size, void* d_ws, size_t ws_size,
                              hipStream_t stream) {
  (void)in_sizes; (void)n_in; (void)out_size; (void)ws_size;
  const float* kin = (const float*)d_in[0];
  const float* qin = (const float*)d_in[1];
  const float* vin = (const float*)d_in[2];
  const float* wk  = (const float*)d_in[4];
  const float* bk  = (const float*)d_in[5];
  const float* wq  = (const float*)d_in[6];
  const float* bq  = (const float*)d_in[7];
  const float* wv  = (const float*)d_in[8];
  const float* bv  = (const float*)d_in[9];
  const float* wo  = (const float*)d_in[10];
  const float* bo  = (const float*)d_in[11];

  unsigned short* ws  = (unsigned short*)d_ws;
  unsigned short* O1  = ws;                        // [B,S,D] fp16 partial (split 1)
  float2* ml0 = (float2*)(ws + 4194304);           // 65536 x float2
  float2* ml1 = (float2*)(ws + 4456448);
  unsigned short* wkb = ws + 12582912;             // fp16 weights
  unsigned short* wqb = ws + 13631488;
  unsigned short* wvb = ws + 14680064;
  unsigned short* wob = ws + 15728640;
  unsigned short* Kp  = ws + 16777216;             // [B,H,S,64]
  unsigned short* Qp  = ws + 20971520;             // [B,H,S,64], pre-scaled 8*log2e
  unsigned short* VpT = ws + 25165824;             // [B,H,64,S]
  unsigned short* Oo  = ws + 29360128;             // [B,S,D] fp16 (split-0 / final)

  cvt_w<<<4096, 256, 0, stream>>>(wk, wq, wv, wo, wkb);
  gemm_proj<<<768, 256, 0, stream>>>(kin, qin, vin, wkb, wqb, wvb,
                                     bk, bq, bv, Kp, Qp, VpT);
  attn_kernel<<<dim3(32, 32, 2), 128, 0, stream>>>(Qp, Kp, VpT, Oo, O1, ml0, ml1);
  merge_o<<<2048, 256, 0, stream>>>(Oo, O1, ml0, ml1);
  gemm_out<<<256, 256, 0, stream>>>(Oo, wob, bo, (float*)d_out);
}